// Round 10
// baseline (215.632 us; speedup 1.0000x reference)
//
#include <hip/hip_runtime.h>
#include <hip/hip_bf16.h>
#include <hip/hip_fp8.h>

#define VOCAB  100000
#define EMB    128
#define NCODES 100000
#define NANC   8

#define ATT_GRID 625           // blocks per attention dispatch (2 dispatches)
#define ATT_TPB  5             // tiles/block: 625*5 = 3125 tiles = 50K codes
#define PRE_GRID 1250          // precompute blocks
#define PRE_TPB  5             // 16-row tiles per block: 1250*5 = 6250 exact

typedef __attribute__((ext_vector_type(8))) short    short8;
typedef __attribute__((ext_vector_type(4))) float    float4v;
typedef __attribute__((ext_vector_type(2))) float    floatx2;
typedef __attribute__((ext_vector_type(4))) unsigned uint4v;
typedef __attribute__((ext_vector_type(2))) __bf16   bf16x2;

__device__ __forceinline__ ushort f2bf(float x) {     // RNE f32 -> bf16 bits
    unsigned u = __float_as_uint(x);
    u += 0x7fffu + ((u >> 16) & 1u);
    return (ushort)(u >> 16);
}
__device__ __forceinline__ float bf2f(ushort h) {
    return __uint_as_float((unsigned)h << 16);
}
// packed f32x2 -> bf16x2 in one dword (v_cvt_pk_bf16_f32 on gfx950, RNE)
__device__ __forceinline__ unsigned pk2bf(float lo, float hi) {
    bf16x2 v;
    v[0] = (__bf16)lo;
    v[1] = (__bf16)hi;
    return __builtin_bit_cast(unsigned, v);
}
__device__ __forceinline__ unsigned char f2fp8(float x) {  // OCP e4m3, RNE+sat
    __hip_fp8_e4m3 t(x);
    return t.__x;
}
// pack 4 f32 -> 4 fp8 bytes in one dword (byte i = v[i], little-endian)
__device__ __forceinline__ unsigned pack_fp8x4(float a, float b, float c, float d) {
#if __has_builtin(__builtin_amdgcn_cvt_pk_fp8_f32)
    int w = __builtin_amdgcn_cvt_pk_fp8_f32(a, b, 0, false);   // bytes 0,1
    w = __builtin_amdgcn_cvt_pk_fp8_f32(c, d, w, true);        // bytes 2,3
    return (unsigned)w;
#else
    return (unsigned)f2fp8(a) | ((unsigned)f2fp8(b) << 8)
         | ((unsigned)f2fp8(c) << 16) | ((unsigned)f2fp8(d) << 24);
#endif
}
// decode 2 fp8 from the low/high 16-bit word of v (HI must be compile-time)
template <bool HI>
__device__ __forceinline__ floatx2 fp8pair(unsigned v) {
#if __has_builtin(__builtin_amdgcn_cvt_pk_f32_fp8)
    return __builtin_amdgcn_cvt_pk_f32_fp8((int)v, HI);
#else
    __hip_fp8_e4m3 a, b;
    const unsigned s = HI ? 16u : 0u;
    a.__x = (v >> s) & 0xffu;
    b.__x = (v >> (s + 8u)) & 0xffu;
    floatx2 r; r[0] = (float)a; r[1] = (float)b; return r;
#endif
}

// Packed-f32 tanh for 2 float2 pairs (4 elems), one v_rcp total.
// tanh(x) ~= x(945+105y+y^2)/(945+420y+15y^2), y=x^2; clamp +-3.5.
__device__ __forceinline__ void tanh2pk(floatx2 za, floatx2 zb,
                                        floatx2& ta, floatx2& tb) {
    floatx2 xa, xb;
    xa[0] = fminf(fmaxf(za[0], -3.5f), 3.5f);   // v_med3_f32
    xa[1] = fminf(fmaxf(za[1], -3.5f), 3.5f);
    xb[0] = fminf(fmaxf(zb[0], -3.5f), 3.5f);
    xb[1] = fminf(fmaxf(zb[1], -3.5f), 3.5f);
    const floatx2 ya = xa * xa, yb = xb * xb;
    floatx2 Na = ya + 105.0f;  Na = ya * Na + 945.0f;       // y^2+105y+945
    floatx2 Nb = yb + 105.0f;  Nb = yb * Nb + 945.0f;
    floatx2 Da = ya * 15.0f + 420.0f;  Da = ya * Da + 945.0f; // 15y^2+420y+945
    floatx2 Db = yb * 15.0f + 420.0f;  Db = yb * Db + 945.0f;
    const floatx2 Dp = Da * Db;
    const float r = __builtin_amdgcn_rcpf(Dp[0] * Dp[1]);   // 1/(prod of 4 D)
    floatx2 qv;  qv[0] = r * Dp[1];  qv[1] = r * Dp[0];
    const floatx2 ia = qv * Db;      // (1/Da0, 1/Da1)
    const floatx2 ib = qv * Da;      // (1/Db0, 1/Db1)
    ta = (xa * Na) * ia;
    tb = (xb * Nb) * ib;
}

// ---------------------------------------------------------------------------
// Kernel A0: WT[c][e] = bf16(W_att[h*128+e][d]), c = h*128+d.  64 KB output.
// ---------------------------------------------------------------------------
__global__ void transpose_watt(const float* __restrict__ W_att,
                               ushort* __restrict__ WT)
{
    const int id = blockIdx.x * 256 + threadIdx.x;   // 32768 total
    const int c = id >> 7, e = id & 127;
    const int h = c >> 7, d = c & 127;
    WT[c * 128 + e] = f2bf(W_att[(h * 128 + e) * 128 + d]);
}

// ---------------------------------------------------------------------------
// Kernel A (r9 state, FROZEN this round for clean measurement): MFMA
// precompute, 2-deep prefetch (neutral vs 1-deep -> not latency-bound),
// cvt_pk conversion, merged-M output, coalesced dwordx4 P-store.
// r10 is a VISIBILITY round: attention is split so this kernel surfaces in
// top-5 (iff >~34us) with its counters for the next decision.
// ---------------------------------------------------------------------------
__global__ __launch_bounds__(256) void precompute(
    const float*  __restrict__ W_emb,   // [VOCAB][128] f32
    const ushort* __restrict__ WT,      // [256][128] bf16 (A0 output)
    const float*  __restrict__ b_att,   // [128]
    unsigned char* __restrict__ P1,     // [VOCAB][128] fp8
    unsigned char* __restrict__ M)      // [VOCAB][384] merged P2|Ebf
{
    const int t = threadIdx.x, wave = t >> 6, lane = t & 63;
    const int n15 = lane & 15, quad = lane >> 4;
    const int cw = wave * 64;                      // this wave's 64 output cols

    // A-operand frags, interleaved col assignment (verified r7):
    short8 wfrag[4][4];                            // [kt][ntl]
    #pragma unroll
    for (int ntl = 0; ntl < 4; ++ntl) {
        const int c = cw + ((n15 >> 2) << 4) + ntl * 4 + (n15 & 3);
        #pragma unroll
        for (int kt = 0; kt < 4; ++kt)
            wfrag[kt][ntl] = *(const short8*)(WT + c * 128 + kt * 32 + quad * 8);
    }

    // bias for out cols cw + quad*16 + ntl*4 + {0..3}  (P1 waves only)
    float4 bb[4];
    #pragma unroll
    for (int ntl = 0; ntl < 4; ++ntl) {
        if (wave < 2) bb[ntl] = *(const float4*)(b_att + cw + quad * 16 + ntl * 4);
        else          bb[ntl] = make_float4(0.f, 0.f, 0.f, 0.f);
    }

    unsigned char* Pt;
    size_t rstride;
    int cbase;   // byte offset of this lane's 16-byte store within its row
    if (wave < 2) { Pt = P1; rstride = 128; cbase = cw + quad * 16; }
    else          { Pt = M;  rstride = 384; cbase = (cw - 128) + quad * 16; }

    const int b = blockIdx.x;          // tiles b + it*PRE_GRID, it = 0..4

#define LOAD_TILE(dst, rtv)                                                   \
    {                                                                         \
        const float4v* src =                                                  \
            (const float4v*)(W_emb + (size_t)((rtv) * 16 + n15) * 128);       \
        _Pragma("unroll")                                                     \
        for (int kt = 0; kt < 4; ++kt) {                                      \
            (dst)[2 * kt]     = __builtin_nontemporal_load(src + kt * 8 + quad * 2);     \
            (dst)[2 * kt + 1] = __builtin_nontemporal_load(src + kt * 8 + quad * 2 + 1); \
        }                                                                     \
    }

    float4v buf[3][8];                 // rotating; indices static after unroll
    LOAD_TILE(buf[0], b)
    LOAD_TILE(buf[1], b + PRE_GRID)

    #pragma unroll
    for (int it = 0; it < PRE_TPB; ++it) {
        // depth-2 prefetch into the buffer freed two iterations ago
        if (it + 2 < PRE_TPB)
            LOAD_TILE(buf[(it + 2) % 3], b + (it + 2) * PRE_GRID)

        const float4v* cur = buf[it % 3];
        const int R = (b + it * PRE_GRID) * 16;

        float4v acc[4];
        #pragma unroll
        for (int i = 0; i < 4; ++i) acc[i] = (float4v)0.0f;

        #pragma unroll
        for (int kt = 0; kt < 4; ++kt) {
            const float4v a0 = cur[2 * kt], a1 = cur[2 * kt + 1];
            uint4v ad;
            ad[0] = pk2bf(a0[0], a0[1]);
            ad[1] = pk2bf(a0[2], a0[3]);
            ad[2] = pk2bf(a1[0], a1[1]);
            ad[3] = pk2bf(a1[2], a1[3]);
            const short8 af = __builtin_bit_cast(short8, ad);
            // Ebf-part store, split across waves 0 (kt 0,1) and 1 (kt 2,3)
            if ((wave < 2) && ((kt >> 1) == wave))
                *(short8*)(M + (size_t)(R + n15) * 384 + 128 + kt * 64 + quad * 16) = af;
            #pragma unroll
            for (int ntl = 0; ntl < 4; ++ntl)
                acc[ntl] = __builtin_amdgcn_mfma_f32_16x16x32_bf16(
                               wfrag[kt][ntl], af, acc[ntl], 0, 0, 0);
        }

        // Epilogue: lane owns row R+n15, 16 consecutive fp8 cols -> dwordx4
        uint4v pks;
        #pragma unroll
        for (int ntl = 0; ntl < 4; ++ntl)
            pks[ntl] = pack_fp8x4(acc[ntl][0] + bb[ntl].x,
                                  acc[ntl][1] + bb[ntl].y,
                                  acc[ntl][2] + bb[ntl].z,
                                  acc[ntl][3] + bb[ntl].w);
        *(uint4v*)(Pt + (size_t)(R + n15) * rstride + cbase) = pks;
    }
#undef LOAD_TILE
}

// ---------------------------------------------------------------------------
// Kernel B (r10): r8's pipelined attention, SPLIT into 2 half-range
// dispatches (tile0 = 0 / 3125) purely for top-5 visibility of precompute.
// Per-code arithmetic bit-identical to r8 (67.2us @3.7TB/s, at pattern
// roofline; occupancy-insensitive per r8, so 625-block dispatches are safe).
// ---------------------------------------------------------------------------
__global__ __launch_bounds__(256) void attention_main(
    const unsigned char* __restrict__ P1,
    const unsigned char* __restrict__ M,
    const float* __restrict__ v_att,
    const int*   __restrict__ leaves, const int* __restrict__ anc,
    float*       __restrict__ out, int tile0)
{
    const int t = threadIdx.x;
    const int wave = t >> 6, lane = t & 63;
    const int sub = lane >> 4, l16 = lane & 15;
    const int jj = l16 & 7;

    floatx2 vv[4];
    #pragma unroll
    for (int p = 0; p < 4; ++p)
        vv[p] = *(const floatx2*)(v_att + l16 * 8 + 2 * p);

    const int base = tile0 + blockIdx.x;   // tiles: base + k*ATT_GRID

    // distributed index pointer for a tile: lane j=l16<8 -> leaf j, else anc
    auto idx_ptr = [&](int tile) -> const int* {
        const int n = tile * 16 + wave * 4 + sub;
        return (l16 & 8) ? (anc + n * 8 + jj) : (leaves + n * 8 + jj);
    };

    int    lf[2][NANC], an[2][NANC];
    uint2  R1[2][NANC], R2[2][NANC];
    short8 EM[NANC];
    int    raw[2];

    // ---- prologue: stage 0 fully issued, stage-1 index in flight ----
    raw[0] = __builtin_nontemporal_load(idx_ptr(base));
    #pragma unroll
    for (int a = 0; a < NANC; ++a) {
        lf[0][a] = __shfl(raw[0], (sub << 4) + a);
        an[0][a] = __shfl(raw[0], (sub << 4) + 8 + a);
    }
    #pragma unroll
    for (int a = 0; a < NANC; ++a)
        R1[0][a] = *(const uint2*)(P1 + (size_t)lf[0][a] * 128 + l16 * 8);
    #pragma unroll
    for (int a = 0; a < NANC; ++a)
        R2[0][a] = *(const uint2*)(M + (size_t)an[0][a] * 384 + l16 * 8);
    #pragma unroll
    for (int a = 0; a < NANC; ++a)
        EM[a] = *(const short8*)(M + (size_t)an[0][a] * 384 + 128 + l16 * 16);
    raw[1] = __builtin_nontemporal_load(idx_ptr(base + ATT_GRID));

    #pragma unroll
    for (int it = 0; it < ATT_TPB; ++it) {
        const int cur = it & 1, nx = cur ^ 1;
        const int tile = base + it * ATT_GRID;

        // stage t+1: resolve indices (in flight since last iter), issue R1/R2
        if (it + 1 < ATT_TPB) {
            #pragma unroll
            for (int a = 0; a < NANC; ++a) {
                lf[nx][a] = __shfl(raw[nx], (sub << 4) + a);
                an[nx][a] = __shfl(raw[nx], (sub << 4) + 8 + a);
            }
            #pragma unroll
            for (int a = 0; a < NANC; ++a)
                R1[nx][a] = *(const uint2*)(P1 + (size_t)lf[nx][a] * 128 + l16 * 8);
            #pragma unroll
            for (int a = 0; a < NANC; ++a)
                R2[nx][a] = *(const uint2*)(M + (size_t)an[nx][a] * 384 + l16 * 8);
        }
        // stage t+2: index load into the slot freed by the current tile
        if (it + 2 < ATT_TPB)
            raw[cur] = __builtin_nontemporal_load(idx_ptr(tile + 2 * ATT_GRID));

        // ---- compute current tile ----
        const int n = tile * 16 + wave * 4 + sub;

        float q[NANC];
        #pragma unroll
        for (int a = 0; a < NANC; ++a) {
            const floatx2 z0 = fp8pair<false>(R1[cur][a].x) + fp8pair<false>(R2[cur][a].x);
            const floatx2 z1 = fp8pair<true >(R1[cur][a].x) + fp8pair<true >(R2[cur][a].x);
            const floatx2 z2 = fp8pair<false>(R1[cur][a].y) + fp8pair<false>(R2[cur][a].y);
            const floatx2 z3 = fp8pair<true >(R1[cur][a].y) + fp8pair<true >(R2[cur][a].y);
            floatx2 t0, t1, t2, t3;
            tanh2pk(z0, z1, t0, t1);
            tanh2pk(z2, z3, t2, t3);
            floatx2 qa = t0 * vv[0];
            qa = t1 * vv[1] + qa;
            qa = t2 * vv[2] + qa;
            qa = t3 * vv[3] + qa;
            q[a] = qa[0] + qa[1];
        }

        // folded reduction over 16 lanes
        float r4[4];
        #pragma unroll
        for (int i = 0; i < 4; ++i) {
            const float keep = (l16 & 8) ? q[i + 4] : q[i];
            const float send = (l16 & 8) ? q[i]     : q[i + 4];
            r4[i] = keep + __shfl_xor(send, 8);
        }
        float s2[2];
        #pragma unroll
        for (int i = 0; i < 2; ++i) {
            const float keep = (l16 & 4) ? r4[i + 2] : r4[i];
            const float send = (l16 & 4) ? r4[i]     : r4[i + 2];
            s2[i] = keep + __shfl_xor(send, 4);
        }
        {
            const float keep = (l16 & 2) ? s2[1] : s2[0];
            const float send = (l16 & 2) ? s2[0] : s2[1];
            s2[0] = keep + __shfl_xor(send, 2);
        }
        float tq = s2[0] + __shfl_xor(s2[0], 1);   // lane holds q_total[A(l)]

        // distributed softmax over the 8 a-groups (lane bits 3,2,1)
        float m = tq;
        m = fmaxf(m, __shfl_xor(m, 8));
        m = fmaxf(m, __shfl_xor(m, 4));
        m = fmaxf(m, __shfl_xor(m, 2));
        const float e = __expf(tq - m);
        float s = e;
        s += __shfl_xor(s, 8); s += __shfl_xor(s, 4); s += __shfl_xor(s, 2);
        const float wl = e * __fdividef(1.0f, s);

        // broadcast the 8 weights to every lane
        float wa[NANC];
        {
            const float p  = __shfl_xor(wl, 2);
            const float w0 = (l16 & 2) ? p  : wl;   // a-bit0 = 0
            const float w1 = (l16 & 2) ? wl : p;    // a-bit0 = 1
            const float p0 = __shfl_xor(w0, 4), p1 = __shfl_xor(w1, 4);
            const float v00 = (l16 & 4) ? p0 : w0, v01 = (l16 & 4) ? p1 : w1;
            const float v10 = (l16 & 4) ? w0 : p0, v11 = (l16 & 4) ? w1 : p1;
            float g;
            g = __shfl_xor(v00, 8); wa[0] = (l16 & 8) ? g : v00; wa[4] = (l16 & 8) ? v00 : g;
            g = __shfl_xor(v01, 8); wa[1] = (l16 & 8) ? g : v01; wa[5] = (l16 & 8) ? v01 : g;
            g = __shfl_xor(v10, 8); wa[2] = (l16 & 8) ? g : v10; wa[6] = (l16 & 8) ? v10 : g;
            g = __shfl_xor(v11, 8); wa[3] = (l16 & 8) ? g : v11; wa[7] = (l16 & 8) ? v11 : g;
        }

        // weighted sum, packed f32 over col pairs (consumes EM -> frees it)
        floatx2 o[4] = {(floatx2)0.f, (floatx2)0.f, (floatx2)0.f, (floatx2)0.f};
        #pragma unroll
        for (int a = 0; a < NANC; ++a) {
            floatx2 wv; wv[0] = wa[a]; wv[1] = wa[a];
            #pragma unroll
            for (int p = 0; p < 4; ++p) {
                floatx2 ev;
                ev[0] = bf2f((ushort)EM[a][2 * p]);
                ev[1] = bf2f((ushort)EM[a][2 * p + 1]);
                o[p] = ev * wv + o[p];
            }
        }
        float4v o1, o2;
        o1[0] = o[0][0]; o1[1] = o[0][1]; o1[2] = o[1][0]; o1[3] = o[1][1];
        o2[0] = o[2][0]; o2[1] = o[2][1]; o2[2] = o[3][0]; o2[3] = o[3][1];
        __builtin_nontemporal_store(o1, (float4v*)(out + (size_t)n * 128 + l16 * 8));
        __builtin_nontemporal_store(o2, (float4v*)(out + (size_t)n * 128 + l16 * 8 + 4));

        // issue next tile's EM into the now-free buffer; consumed next iter
        if (it + 1 < ATT_TPB) {
            #pragma unroll
            for (int a = 0; a < NANC; ++a)
                EM[a] = *(const short8*)(M + (size_t)an[nx][a] * 384 + 128 + l16 * 16);
        }
    }
}

// ---------------------------------------------------------------------------
extern "C" void kernel_launch(void* const* d_in, const int* in_sizes, int n_in,
                              void* d_out, int out_size, void* d_ws, size_t ws_size,
                              hipStream_t stream) {
    const float* W_emb  = (const float*)d_in[0];
    const float* W_att  = (const float*)d_in[1];
    const float* b_att  = (const float*)d_in[2];
    const float* v_att  = (const float*)d_in[3];
    const int*   leaves = (const int*)d_in[4];
    const int*   anc    = (const int*)d_in[5];
    float*       out    = (float*)d_out;

    unsigned char* P1 = (unsigned char*)d_ws;            // 12.8 MB fp8
    unsigned char* M  = P1 + (size_t)VOCAB * 128;        // 38.4 MB merged
    ushort* WT = (ushort*)(M + (size_t)VOCAB * 384);     // 64 KB bf16

    transpose_watt<<<128, 256, 0, stream>>>(W_att, WT);
    precompute<<<PRE_GRID, 256, 0, stream>>>(W_emb, WT, b_att, P1, M);
    attention_main<<<ATT_GRID, 256, 0, stream>>>(P1, M, v_att,
                                                 leaves, anc, out, 0);
    attention_main<<<ATT_GRID, 256, 0, stream>>>(P1, M, v_att,
                                                 leaves, anc, out, 3125);
}

// Round 11
// 196.047 us; speedup vs baseline: 1.0999x; 1.0999x over previous
//
#include <hip/hip_runtime.h>
#include <hip/hip_bf16.h>
#include <hip/hip_fp8.h>

#define VOCAB  100000
#define EMB    128
#define NCODES 100000
#define NANC   8

#define ATT_GRID 625           // blocks per attention dispatch (2 dispatches)
#define ATT_TPB  5             // tiles/block: 625*5 = 3125 tiles = 50K codes
#define PRE_GRID 1250          // precompute blocks
#define PRE_TPB  5             // 16-row tiles per block: 1250*5 = 6250 exact

typedef __attribute__((ext_vector_type(8))) short    short8;
typedef __attribute__((ext_vector_type(4))) float    float4v;
typedef __attribute__((ext_vector_type(2))) float    floatx2;
typedef __attribute__((ext_vector_type(4))) unsigned uint4v;
typedef __attribute__((ext_vector_type(2))) __bf16   bf16x2;

__device__ __forceinline__ ushort f2bf(float x) {     // RNE f32 -> bf16 bits
    unsigned u = __float_as_uint(x);
    u += 0x7fffu + ((u >> 16) & 1u);
    return (ushort)(u >> 16);
}
__device__ __forceinline__ float bf2f(ushort h) {
    return __uint_as_float((unsigned)h << 16);
}
// packed f32x2 -> bf16x2 in one dword (v_cvt_pk_bf16_f32 on gfx950, RNE)
__device__ __forceinline__ unsigned pk2bf(float lo, float hi) {
    bf16x2 v;
    v[0] = (__bf16)lo;
    v[1] = (__bf16)hi;
    return __builtin_bit_cast(unsigned, v);
}
__device__ __forceinline__ unsigned char f2fp8(float x) {  // OCP e4m3, RNE+sat
    __hip_fp8_e4m3 t(x);
    return t.__x;
}
// pack 4 f32 -> 4 fp8 bytes in one dword (byte i = v[i], little-endian)
__device__ __forceinline__ unsigned pack_fp8x4(float a, float b, float c, float d) {
#if __has_builtin(__builtin_amdgcn_cvt_pk_fp8_f32)
    int w = __builtin_amdgcn_cvt_pk_fp8_f32(a, b, 0, false);   // bytes 0,1
    w = __builtin_amdgcn_cvt_pk_fp8_f32(c, d, w, true);        // bytes 2,3
    return (unsigned)w;
#else
    return (unsigned)f2fp8(a) | ((unsigned)f2fp8(b) << 8)
         | ((unsigned)f2fp8(c) << 16) | ((unsigned)f2fp8(d) << 24);
#endif
}
// decode 2 fp8 from the low/high 16-bit word of v (HI must be compile-time)
template <bool HI>
__device__ __forceinline__ floatx2 fp8pair(unsigned v) {
#if __has_builtin(__builtin_amdgcn_cvt_pk_f32_fp8)
    return __builtin_amdgcn_cvt_pk_f32_fp8((int)v, HI);
#else
    __hip_fp8_e4m3 a, b;
    const unsigned s = HI ? 16u : 0u;
    a.__x = (v >> s) & 0xffu;
    b.__x = (v >> (s + 8u)) & 0xffu;
    floatx2 r; r[0] = (float)a; r[1] = (float)b; return r;
#endif
}

// Packed-f32 tanh for 2 float2 pairs (4 elems), one v_rcp total.
// tanh(x) ~= x(945+105y+y^2)/(945+420y+15y^2), y=x^2; clamp +-3.5.
__device__ __forceinline__ void tanh2pk(floatx2 za, floatx2 zb,
                                        floatx2& ta, floatx2& tb) {
    floatx2 xa, xb;
    xa[0] = fminf(fmaxf(za[0], -3.5f), 3.5f);   // v_med3_f32
    xa[1] = fminf(fmaxf(za[1], -3.5f), 3.5f);
    xb[0] = fminf(fmaxf(zb[0], -3.5f), 3.5f);
    xb[1] = fminf(fmaxf(zb[1], -3.5f), 3.5f);
    const floatx2 ya = xa * xa, yb = xb * xb;
    floatx2 Na = ya + 105.0f;  Na = ya * Na + 945.0f;       // y^2+105y+945
    floatx2 Nb = yb + 105.0f;  Nb = yb * Nb + 945.0f;
    floatx2 Da = ya * 15.0f + 420.0f;  Da = ya * Da + 945.0f; // 15y^2+420y+945
    floatx2 Db = yb * 15.0f + 420.0f;  Db = yb * Db + 945.0f;
    const floatx2 Dp = Da * Db;
    const float r = __builtin_amdgcn_rcpf(Dp[0] * Dp[1]);   // 1/(prod of 4 D)
    floatx2 qv;  qv[0] = r * Dp[1];  qv[1] = r * Dp[0];
    const floatx2 ia = qv * Db;      // (1/Da0, 1/Da1)
    const floatx2 ib = qv * Da;      // (1/Db0, 1/Db1)
    ta = (xa * Na) * ia;
    tb = (xb * Nb) * ib;
}

// ---------------------------------------------------------------------------
// Kernel A0: WT[c][e] = bf16(W_att[h*128+e][d]), c = h*128+d.  64 KB output.
// ---------------------------------------------------------------------------
__global__ void transpose_watt(const float* __restrict__ W_att,
                               ushort* __restrict__ WT)
{
    const int id = blockIdx.x * 256 + threadIdx.x;   // 32768 total
    const int c = id >> 7, e = id & 127;
    const int h = c >> 7, d = c & 127;
    WT[c * 128 + e] = f2bf(W_att[(h * 128 + e) * 128 + d]);
}

// ---------------------------------------------------------------------------
// Kernel A (r11): LDS-staged MFMA precompute.
// r10 counters: 55us, VGPR=120, VALUBusy 6.8%, hbm 2.0 TB/s, everything
// idle.  The written schedule needs ~176 live VGPRs (buf 96 + wfrag 64 +
// bb 16); at 120 allocated the compiler provably could NOT keep the
// prefetch buffers resident -> it re-serialized loads against uses, which
// is why depth-1 == depth-2 == neutral.  Fix: stage the W_emb tile in LDS
// via global_load_lds DMA (no VGPR round-trip, ONE copy per block instead
// of 4 redundant per-wave copies).  Single-buffered + syncthreads: simplest
// correct structure; per-block serial DMA+compute ~7.5K cy is TLP-covered
// once VGPR drops to ~100 (4 blocks/CU).  f32 bits round-trip LDS
// losslessly -> output tables bit-identical (absmax gate 0.0234375).
// ---------------------------------------------------------------------------
__global__ __launch_bounds__(256) void precompute(
    const float*  __restrict__ W_emb,   // [VOCAB][128] f32
    const ushort* __restrict__ WT,      // [256][128] bf16 (A0 output)
    const float*  __restrict__ b_att,   // [128]
    unsigned char* __restrict__ P1,     // [VOCAB][128] fp8
    unsigned char* __restrict__ M)      // [VOCAB][384] merged P2|Ebf
{
    __shared__ __align__(16) float lds[2048];      // one 16x128 f32 tile, 8KB

    const int t = threadIdx.x, wave = t >> 6, lane = t & 63;
    const int n15 = lane & 15, quad = lane >> 4;
    const int cw = wave * 64;                      // this wave's 64 output cols

    // A-operand frags, interleaved col assignment (verified r7):
    short8 wfrag[4][4];                            // [kt][ntl]
    #pragma unroll
    for (int ntl = 0; ntl < 4; ++ntl) {
        const int c = cw + ((n15 >> 2) << 4) + ntl * 4 + (n15 & 3);
        #pragma unroll
        for (int kt = 0; kt < 4; ++kt)
            wfrag[kt][ntl] = *(const short8*)(WT + c * 128 + kt * 32 + quad * 8);
    }

    // bias for out cols cw + quad*16 + ntl*4 + {0..3}  (P1 waves only)
    float4 bb[4];
    #pragma unroll
    for (int ntl = 0; ntl < 4; ++ntl) {
        if (wave < 2) bb[ntl] = *(const float4*)(b_att + cw + quad * 16 + ntl * 4);
        else          bb[ntl] = make_float4(0.f, 0.f, 0.f, 0.f);
    }

    unsigned char* Pt;
    size_t rstride;
    int cbase;   // byte offset of this lane's 16-byte store within its row
    if (wave < 2) { Pt = P1; rstride = 128; cbase = cw + quad * 16; }
    else          { Pt = M;  rstride = 384; cbase = (cw - 128) + quad * 16; }

    const int b = blockIdx.x;          // tiles b + it*PRE_GRID, it = 0..4

    // This thread's source element within a tile, per 4KB chunk c:
    //   tile byte x = c*4096 + t*16 ; row = x>>9 ; col_floats = (t&31)*4
    const int r0 = t >> 5, cf = (t & 31) * 4;      // chunk0: row r0
                                                   // chunk1: row r0 + 8

    #pragma unroll
    for (int it = 0; it < PRE_TPB; ++it) {
        const int rt = b + it * PRE_GRID;
        const float* tb0 = W_emb + (size_t)rt * 2048;   // 16*128 floats

#if __has_builtin(__builtin_amdgcn_global_load_lds)
        // DMA 8KB tile: 2 chunks x (4 waves x 64 lanes x 16B).
        // LDS dest is wave-uniform base + lane*16 (linear); global src per-lane.
        __builtin_amdgcn_global_load_lds(
            (const __attribute__((address_space(1))) void*)(tb0 + r0 * 128 + cf),
            (__attribute__((address_space(3))) void*)&lds[wave * 256],
            16, 0, 0);
        __builtin_amdgcn_global_load_lds(
            (const __attribute__((address_space(1))) void*)(tb0 + (r0 + 8) * 128 + cf),
            (__attribute__((address_space(3))) void*)&lds[1024 + wave * 256],
            16, 0, 0);
        asm volatile("s_waitcnt vmcnt(0)" ::: "memory");
#else
        // fallback: reg-staged copy (transient 8 VGPRs)
        const float4v v0 = *(const float4v*)(tb0 + r0 * 128 + cf);
        const float4v v1 = *(const float4v*)(tb0 + (r0 + 8) * 128 + cf);
        *(float4v*)&lds[t * 4]        = v0;
        *(float4v*)&lds[1024 + t * 4] = v1;
#endif
        __syncthreads();               // tile visible to all waves

        const int R = rt * 16;
        float4v acc[4];
        #pragma unroll
        for (int i = 0; i < 4; ++i) acc[i] = (float4v)0.0f;

        #pragma unroll
        for (int kt = 0; kt < 4; ++kt) {
            // lane reads row n15, floats kt*32 + quad*8 .. +7 from LDS
            const float4v a0 = *(const float4v*)&lds[n15 * 128 + kt * 32 + quad * 8];
            const float4v a1 = *(const float4v*)&lds[n15 * 128 + kt * 32 + quad * 8 + 4];
            uint4v ad;
            ad[0] = pk2bf(a0[0], a0[1]);
            ad[1] = pk2bf(a0[2], a0[3]);
            ad[2] = pk2bf(a1[0], a1[1]);
            ad[3] = pk2bf(a1[2], a1[3]);
            const short8 af = __builtin_bit_cast(short8, ad);
            // Ebf-part store, split across waves 0 (kt 0,1) and 1 (kt 2,3)
            if ((wave < 2) && ((kt >> 1) == wave))
                *(short8*)(M + (size_t)(R + n15) * 384 + 128 + kt * 64 + quad * 16) = af;
            #pragma unroll
            for (int ntl = 0; ntl < 4; ++ntl)
                acc[ntl] = __builtin_amdgcn_mfma_f32_16x16x32_bf16(
                               wfrag[kt][ntl], af, acc[ntl], 0, 0, 0);
        }

        // Epilogue: lane owns row R+n15, 16 consecutive fp8 cols -> dwordx4
        uint4v pks;
        #pragma unroll
        for (int ntl = 0; ntl < 4; ++ntl)
            pks[ntl] = pack_fp8x4(acc[ntl][0] + bb[ntl].x,
                                  acc[ntl][1] + bb[ntl].y,
                                  acc[ntl][2] + bb[ntl].z,
                                  acc[ntl][3] + bb[ntl].w);
        *(uint4v*)(Pt + (size_t)(R + n15) * rstride + cbase) = pks;

        if (it + 1 < PRE_TPB)
            __syncthreads();           // readers done before next DMA overwrite
    }
}

// ---------------------------------------------------------------------------
// Kernel B (FROZEN, split r10 config kept for measurement isolation):
// pipelined attention, 2 half-range dispatches.  At pattern roofline
// (3.7 TB/s random 128B-line gathers; ILP- and occupancy-insensitive).
// ---------------------------------------------------------------------------
__global__ __launch_bounds__(256) void attention_main(
    const unsigned char* __restrict__ P1,
    const unsigned char* __restrict__ M,
    const float* __restrict__ v_att,
    const int*   __restrict__ leaves, const int* __restrict__ anc,
    float*       __restrict__ out, int tile0)
{
    const int t = threadIdx.x;
    const int wave = t >> 6, lane = t & 63;
    const int sub = lane >> 4, l16 = lane & 15;
    const int jj = l16 & 7;

    floatx2 vv[4];
    #pragma unroll
    for (int p = 0; p < 4; ++p)
        vv[p] = *(const floatx2*)(v_att + l16 * 8 + 2 * p);

    const int base = tile0 + blockIdx.x;   // tiles: base + k*ATT_GRID

    auto idx_ptr = [&](int tile) -> const int* {
        const int n = tile * 16 + wave * 4 + sub;
        return (l16 & 8) ? (anc + n * 8 + jj) : (leaves + n * 8 + jj);
    };

    int    lf[2][NANC], an[2][NANC];
    uint2  R1[2][NANC], R2[2][NANC];
    short8 EM[NANC];
    int    raw[2];

    // ---- prologue: stage 0 fully issued, stage-1 index in flight ----
    raw[0] = __builtin_nontemporal_load(idx_ptr(base));
    #pragma unroll
    for (int a = 0; a < NANC; ++a) {
        lf[0][a] = __shfl(raw[0], (sub << 4) + a);
        an[0][a] = __shfl(raw[0], (sub << 4) + 8 + a);
    }
    #pragma unroll
    for (int a = 0; a < NANC; ++a)
        R1[0][a] = *(const uint2*)(P1 + (size_t)lf[0][a] * 128 + l16 * 8);
    #pragma unroll
    for (int a = 0; a < NANC; ++a)
        R2[0][a] = *(const uint2*)(M + (size_t)an[0][a] * 384 + l16 * 8);
    #pragma unroll
    for (int a = 0; a < NANC; ++a)
        EM[a] = *(const short8*)(M + (size_t)an[0][a] * 384 + 128 + l16 * 16);
    raw[1] = __builtin_nontemporal_load(idx_ptr(base + ATT_GRID));

    #pragma unroll
    for (int it = 0; it < ATT_TPB; ++it) {
        const int cur = it & 1, nx = cur ^ 1;
        const int tile = base + it * ATT_GRID;

        if (it + 1 < ATT_TPB) {
            #pragma unroll
            for (int a = 0; a < NANC; ++a) {
                lf[nx][a] = __shfl(raw[nx], (sub << 4) + a);
                an[nx][a] = __shfl(raw[nx], (sub << 4) + 8 + a);
            }
            #pragma unroll
            for (int a = 0; a < NANC; ++a)
                R1[nx][a] = *(const uint2*)(P1 + (size_t)lf[nx][a] * 128 + l16 * 8);
            #pragma unroll
            for (int a = 0; a < NANC; ++a)
                R2[nx][a] = *(const uint2*)(M + (size_t)an[nx][a] * 384 + l16 * 8);
        }
        if (it + 2 < ATT_TPB)
            raw[cur] = __builtin_nontemporal_load(idx_ptr(tile + 2 * ATT_GRID));

        const int n = tile * 16 + wave * 4 + sub;

        float q[NANC];
        #pragma unroll
        for (int a = 0; a < NANC; ++a) {
            const floatx2 z0 = fp8pair<false>(R1[cur][a].x) + fp8pair<false>(R2[cur][a].x);
            const floatx2 z1 = fp8pair<true >(R1[cur][a].x) + fp8pair<true >(R2[cur][a].x);
            const floatx2 z2 = fp8pair<false>(R1[cur][a].y) + fp8pair<false>(R2[cur][a].y);
            const floatx2 z3 = fp8pair<true >(R1[cur][a].y) + fp8pair<true >(R2[cur][a].y);
            floatx2 t0, t1, t2, t3;
            tanh2pk(z0, z1, t0, t1);
            tanh2pk(z2, z3, t2, t3);
            floatx2 qa = t0 * vv[0];
            qa = t1 * vv[1] + qa;
            qa = t2 * vv[2] + qa;
            qa = t3 * vv[3] + qa;
            q[a] = qa[0] + qa[1];
        }

        float r4[4];
        #pragma unroll
        for (int i = 0; i < 4; ++i) {
            const float keep = (l16 & 8) ? q[i + 4] : q[i];
            const float send = (l16 & 8) ? q[i]     : q[i + 4];
            r4[i] = keep + __shfl_xor(send, 8);
        }
        float s2[2];
        #pragma unroll
        for (int i = 0; i < 2; ++i) {
            const float keep = (l16 & 4) ? r4[i + 2] : r4[i];
            const float send = (l16 & 4) ? r4[i]     : r4[i + 2];
            s2[i] = keep + __shfl_xor(send, 4);
        }
        {
            const float keep = (l16 & 2) ? s2[1] : s2[0];
            const float send = (l16 & 2) ? s2[0] : s2[1];
            s2[0] = keep + __shfl_xor(send, 2);
        }
        float tq = s2[0] + __shfl_xor(s2[0], 1);   // lane holds q_total[A(l)]

        float m = tq;
        m = fmaxf(m, __shfl_xor(m, 8));
        m = fmaxf(m, __shfl_xor(m, 4));
        m = fmaxf(m, __shfl_xor(m, 2));
        const float e = __expf(tq - m);
        float s = e;
        s += __shfl_xor(s, 8); s += __shfl_xor(s, 4); s += __shfl_xor(s, 2);
        const float wl = e * __fdividef(1.0f, s);

        float wa[NANC];
        {
            const float p  = __shfl_xor(wl, 2);
            const float w0 = (l16 & 2) ? p  : wl;   // a-bit0 = 0
            const float w1 = (l16 & 2) ? wl : p;    // a-bit0 = 1
            const float p0 = __shfl_xor(w0, 4), p1 = __shfl_xor(w1, 4);
            const float v00 = (l16 & 4) ? p0 : w0, v01 = (l16 & 4) ? p1 : w1;
            const float v10 = (l16 & 4) ? w0 : p0, v11 = (l16 & 4) ? w1 : p1;
            float g;
            g = __shfl_xor(v00, 8); wa[0] = (l16 & 8) ? g : v00; wa[4] = (l16 & 8) ? v00 : g;
            g = __shfl_xor(v01, 8); wa[1] = (l16 & 8) ? g : v01; wa[5] = (l16 & 8) ? v01 : g;
            g = __shfl_xor(v10, 8); wa[2] = (l16 & 8) ? g : v10; wa[6] = (l16 & 8) ? v10 : g;
            g = __shfl_xor(v11, 8); wa[3] = (l16 & 8) ? g : v11; wa[7] = (l16 & 8) ? v11 : g;
        }

        floatx2 o[4] = {(floatx2)0.f, (floatx2)0.f, (floatx2)0.f, (floatx2)0.f};
        #pragma unroll
        for (int a = 0; a < NANC; ++a) {
            floatx2 wv; wv[0] = wa[a]; wv[1] = wa[a];
            #pragma unroll
            for (int p = 0; p < 4; ++p) {
                floatx2 ev;
                ev[0] = bf2f((ushort)EM[a][2 * p]);
                ev[1] = bf2f((ushort)EM[a][2 * p + 1]);
                o[p] = ev * wv + o[p];
            }
        }
        float4v o1, o2;
        o1[0] = o[0][0]; o1[1] = o[0][1]; o1[2] = o[1][0]; o1[3] = o[1][1];
        o2[0] = o[2][0]; o2[1] = o[2][1]; o2[2] = o[3][0]; o2[3] = o[3][1];
        __builtin_nontemporal_store(o1, (float4v*)(out + (size_t)n * 128 + l16 * 8));
        __builtin_nontemporal_store(o2, (float4v*)(out + (size_t)n * 128 + l16 * 8 + 4));

        if (it + 1 < ATT_TPB) {
            #pragma unroll
            for (int a = 0; a < NANC; ++a)
                EM[a] = *(const short8*)(M + (size_t)an[nx][a] * 384 + 128 + l16 * 16);
        }
    }
}

// ---------------------------------------------------------------------------
extern "C" void kernel_launch(void* const* d_in, const int* in_sizes, int n_in,
                              void* d_out, int out_size, void* d_ws, size_t ws_size,
                              hipStream_t stream) {
    const float* W_emb  = (const float*)d_in[0];
    const float* W_att  = (const float*)d_in[1];
    const float* b_att  = (const float*)d_in[2];
    const float* v_att  = (const float*)d_in[3];
    const int*   leaves = (const int*)d_in[4];
    const int*   anc    = (const int*)d_in[5];
    float*       out    = (float*)d_out;

    unsigned char* P1 = (unsigned char*)d_ws;            // 12.8 MB fp8
    unsigned char* M  = P1 + (size_t)VOCAB * 128;        // 38.4 MB merged
    ushort* WT = (ushort*)(M + (size_t)VOCAB * 384);     // 64 KB bf16

    transpose_watt<<<128, 256, 0, stream>>>(W_att, WT);
    precompute<<<PRE_GRID, 256, 0, stream>>>(W_emb, WT, b_att, P1, M);
    attention_main<<<ATT_GRID, 256, 0, stream>>>(P1, M, v_att,
                                                 leaves, anc, out, 0);
    attention_main<<<ATT_GRID, 256, 0, stream>>>(P1, M, v_att,
                                                 leaves, anc, out, 3125);
}

// Round 13
// 188.857 us; speedup vs baseline: 1.1418x; 1.0381x over previous
//
#include <hip/hip_runtime.h>
#include <hip/hip_bf16.h>
#include <hip/hip_fp8.h>

#define VOCAB  100000
#define EMB    128
#define NCODES 100000
#define NANC   8

#define ATT_GRID 1250          // attention blocks (single dispatch again)
#define ATT_TPB  5             // tiles/block: 1250*5 = 6250 exact
#define PRE_GRID 1250          // precompute blocks
#define PRE_TPB  5             // 16-row tiles per block: 1250*5 = 6250 exact

typedef __attribute__((ext_vector_type(8))) short    short8;
typedef __attribute__((ext_vector_type(4))) float    float4v;
typedef __attribute__((ext_vector_type(2))) float    floatx2;
typedef __attribute__((ext_vector_type(4))) unsigned uint4v;
typedef __attribute__((ext_vector_type(2))) __bf16   bf16x2;

__device__ __forceinline__ ushort f2bf(float x) {     // RNE f32 -> bf16 bits
    unsigned u = __float_as_uint(x);
    u += 0x7fffu + ((u >> 16) & 1u);
    return (ushort)(u >> 16);
}
__device__ __forceinline__ float bf2f(ushort h) {
    return __uint_as_float((unsigned)h << 16);
}
// packed f32x2 -> bf16x2 in one dword (v_cvt_pk_bf16_f32 on gfx950, RNE)
__device__ __forceinline__ unsigned pk2bf(float lo, float hi) {
    bf16x2 v;
    v[0] = (__bf16)lo;
    v[1] = (__bf16)hi;
    return __builtin_bit_cast(unsigned, v);
}
__device__ __forceinline__ unsigned char f2fp8(float x) {  // OCP e4m3, RNE+sat
    __hip_fp8_e4m3 t(x);
    return t.__x;
}
// pack 4 f32 -> 4 fp8 bytes in one dword (byte i = v[i], little-endian)
__device__ __forceinline__ unsigned pack_fp8x4(float a, float b, float c, float d) {
#if __has_builtin(__builtin_amdgcn_cvt_pk_fp8_f32)
    int w = __builtin_amdgcn_cvt_pk_fp8_f32(a, b, 0, false);   // bytes 0,1
    w = __builtin_amdgcn_cvt_pk_fp8_f32(c, d, w, true);        // bytes 2,3
    return (unsigned)w;
#else
    return (unsigned)f2fp8(a) | ((unsigned)f2fp8(b) << 8)
         | ((unsigned)f2fp8(c) << 16) | ((unsigned)f2fp8(d) << 24);
#endif
}
// decode 2 fp8 from the low/high 16-bit word of v (HI must be compile-time)
template <bool HI>
__device__ __forceinline__ floatx2 fp8pair(unsigned v) {
#if __has_builtin(__builtin_amdgcn_cvt_pk_f32_fp8)
    return __builtin_amdgcn_cvt_pk_f32_fp8((int)v, HI);
#else
    __hip_fp8_e4m3 a, b;
    const unsigned s = HI ? 16u : 0u;
    a.__x = (v >> s) & 0xffu;
    b.__x = (v >> (s + 8u)) & 0xffu;
    floatx2 r; r[0] = (float)a; r[1] = (float)b; return r;
#endif
}

// Packed-f32 tanh for 2 float2 pairs (4 elems), one v_rcp total.
// tanh(x) ~= x(945+105y+y^2)/(945+420y+15y^2), y=x^2; clamp +-3.5.
__device__ __forceinline__ void tanh2pk(floatx2 za, floatx2 zb,
                                        floatx2& ta, floatx2& tb) {
    floatx2 xa, xb;
    xa[0] = fminf(fmaxf(za[0], -3.5f), 3.5f);   // v_med3_f32
    xa[1] = fminf(fmaxf(za[1], -3.5f), 3.5f);
    xb[0] = fminf(fmaxf(zb[0], -3.5f), 3.5f);
    xb[1] = fminf(fmaxf(zb[1], -3.5f), 3.5f);
    const floatx2 ya = xa * xa, yb = xb * xb;
    floatx2 Na = ya + 105.0f;  Na = ya * Na + 945.0f;       // y^2+105y+945
    floatx2 Nb = yb + 105.0f;  Nb = yb * Nb + 945.0f;
    floatx2 Da = ya * 15.0f + 420.0f;  Da = ya * Da + 945.0f; // 15y^2+420y+945
    floatx2 Db = yb * 15.0f + 420.0f;  Db = yb * Db + 945.0f;
    const floatx2 Dp = Da * Db;
    const float r = __builtin_amdgcn_rcpf(Dp[0] * Dp[1]);   // 1/(prod of 4 D)
    floatx2 qv;  qv[0] = r * Dp[1];  qv[1] = r * Dp[0];
    const floatx2 ia = qv * Db;      // (1/Da0, 1/Da1)
    const floatx2 ib = qv * Da;      // (1/Db0, 1/Db1)
    ta = (xa * Na) * ia;
    tb = (xb * Nb) * ib;
}

// ---------------------------------------------------------------------------
// Kernel A0: WT[c][e] = bf16(W_att[h*128+e][d]), c = h*128+d.  64 KB output.
// ---------------------------------------------------------------------------
__global__ void transpose_watt(const float* __restrict__ W_att,
                               ushort* __restrict__ WT)
{
    const int id = blockIdx.x * 256 + threadIdx.x;   // 32768 total
    const int c = id >> 7, e = id & 127;
    const int h = c >> 7, d = c & 127;
    WT[c * 128 + e] = f2bf(W_att[(h * 128 + e) * 128 + d]);
}

// ---------------------------------------------------------------------------
// Kernel A (r12): LDS-staged precompute, DOUBLE-BUFFERED DMA.
// r11 (single-buffer, 55->~30us) still exposes the full ~900cy DMA round
// trip serially per tile (DMA -> vmcnt(0) -> sync -> compute).  Since
// __syncthreads() emits vmcnt(0) anyway, reorder to:
//     sync  ->  issue DMA(tile t+1, other buf)  ->  compute(tile t)
// so the barrier at iteration top drains a DMA issued a full compute-phase
// ago (already landed) instead of a just-issued one.  Overwrite safety is
// barrier-enforced: DMA into buf[nx] is issued only after the barrier that
// proves all waves finished reading buf[nx] (read in iter t-1).  No inline
// asm, no counted vmcnt, one __syncthreads per iter.  Numerics identical
// (absmax gate 0.0234375).  LDS 16KB/block.
// ---------------------------------------------------------------------------
__global__ __launch_bounds__(256) void precompute(
    const float*  __restrict__ W_emb,   // [VOCAB][128] f32
    const ushort* __restrict__ WT,      // [256][128] bf16 (A0 output)
    const float*  __restrict__ b_att,   // [128]
    unsigned char* __restrict__ P1,     // [VOCAB][128] fp8
    unsigned char* __restrict__ M)      // [VOCAB][384] merged P2|Ebf
{
    __shared__ __align__(16) float lds[2 * 2048];  // two 16x128 f32 tiles

    const int t = threadIdx.x, wave = t >> 6, lane = t & 63;
    const int n15 = lane & 15, quad = lane >> 4;
    const int cw = wave * 64;                      // this wave's 64 output cols

    // A-operand frags, interleaved col assignment (verified r7):
    short8 wfrag[4][4];                            // [kt][ntl]
    #pragma unroll
    for (int ntl = 0; ntl < 4; ++ntl) {
        const int c = cw + ((n15 >> 2) << 4) + ntl * 4 + (n15 & 3);
        #pragma unroll
        for (int kt = 0; kt < 4; ++kt)
            wfrag[kt][ntl] = *(const short8*)(WT + c * 128 + kt * 32 + quad * 8);
    }

    // bias for out cols cw + quad*16 + ntl*4 + {0..3}  (P1 waves only)
    float4 bb[4];
    #pragma unroll
    for (int ntl = 0; ntl < 4; ++ntl) {
        if (wave < 2) bb[ntl] = *(const float4*)(b_att + cw + quad * 16 + ntl * 4);
        else          bb[ntl] = make_float4(0.f, 0.f, 0.f, 0.f);
    }

    unsigned char* Pt;
    size_t rstride;
    int cbase;   // byte offset of this lane's 16-byte store within its row
    if (wave < 2) { Pt = P1; rstride = 128; cbase = cw + quad * 16; }
    else          { Pt = M;  rstride = 384; cbase = (cw - 128) + quad * 16; }

    const int b = blockIdx.x;          // tiles b + it*PRE_GRID, it = 0..4

    // This thread's source element within a tile, per 4KB chunk:
    //   chunk0 covers rows 0-7 (row r0), chunk1 rows 8-15 (row r0+8).
    const int r0 = t >> 5, cf = (t & 31) * 4;

#if __has_builtin(__builtin_amdgcn_global_load_lds)
#define DMA_TILE(bufi, rtv)                                                   \
    {                                                                         \
        const float* tb0 = W_emb + (size_t)(rtv) * 2048;                      \
        __builtin_amdgcn_global_load_lds(                                     \
            (const __attribute__((address_space(1))) void*)(tb0 + r0 * 128 + cf), \
            (__attribute__((address_space(3))) void*)&lds[(bufi) * 2048 + wave * 256], \
            16, 0, 0);                                                        \
        __builtin_amdgcn_global_load_lds(                                     \
            (const __attribute__((address_space(1))) void*)(tb0 + (r0 + 8) * 128 + cf), \
            (__attribute__((address_space(3))) void*)&lds[(bufi) * 2048 + 1024 + wave * 256], \
            16, 0, 0);                                                        \
    }
#else
#define DMA_TILE(bufi, rtv)                                                   \
    {                                                                         \
        const float* tb0 = W_emb + (size_t)(rtv) * 2048;                      \
        const float4v v0 = *(const float4v*)(tb0 + r0 * 128 + cf);            \
        const float4v v1 = *(const float4v*)(tb0 + (r0 + 8) * 128 + cf);      \
        *(float4v*)&lds[(bufi) * 2048 + t * 4]        = v0;                   \
        *(float4v*)&lds[(bufi) * 2048 + 1024 + t * 4] = v1;                   \
    }
#endif

    DMA_TILE(0, b)                     // prologue: tile 0 into buffer 0

    #pragma unroll
    for (int it = 0; it < PRE_TPB; ++it) {
        // drains tile-it DMA (issued one compute-phase ago) + aligns waves
        __syncthreads();
        // issue next tile into the other buffer; lands during compute(it)
        if (it + 1 < PRE_TPB)
            DMA_TILE((it + 1) & 1, b + (it + 1) * PRE_GRID)

        const int rt = b + it * PRE_GRID;
        const int R = rt * 16;
        const float* lb = &lds[(it & 1) * 2048];

        float4v acc[4];
        #pragma unroll
        for (int i = 0; i < 4; ++i) acc[i] = (float4v)0.0f;

        #pragma unroll
        for (int kt = 0; kt < 4; ++kt) {
            // lane reads row n15, floats kt*32 + quad*8 .. +7 from LDS
            const float4v a0 = *(const float4v*)&lb[n15 * 128 + kt * 32 + quad * 8];
            const float4v a1 = *(const float4v*)&lb[n15 * 128 + kt * 32 + quad * 8 + 4];
            uint4v ad;
            ad[0] = pk2bf(a0[0], a0[1]);
            ad[1] = pk2bf(a0[2], a0[3]);
            ad[2] = pk2bf(a1[0], a1[1]);
            ad[3] = pk2bf(a1[2], a1[3]);
            const short8 af = __builtin_bit_cast(short8, ad);
            // Ebf-part store, split across waves 0 (kt 0,1) and 1 (kt 2,3)
            if ((wave < 2) && ((kt >> 1) == wave))
                *(short8*)(M + (size_t)(R + n15) * 384 + 128 + kt * 64 + quad * 16) = af;
            #pragma unroll
            for (int ntl = 0; ntl < 4; ++ntl)
                acc[ntl] = __builtin_amdgcn_mfma_f32_16x16x32_bf16(
                               wfrag[kt][ntl], af, acc[ntl], 0, 0, 0);
        }

        // Epilogue: lane owns row R+n15, 16 consecutive fp8 cols -> dwordx4
        uint4v pks;
        #pragma unroll
        for (int ntl = 0; ntl < 4; ++ntl)
            pks[ntl] = pack_fp8x4(acc[ntl][0] + bb[ntl].x,
                                  acc[ntl][1] + bb[ntl].y,
                                  acc[ntl][2] + bb[ntl].z,
                                  acc[ntl][3] + bb[ntl].w);
        *(uint4v*)(Pt + (size_t)(R + n15) * rstride + cbase) = pks;
    }
#undef DMA_TILE
}

// ---------------------------------------------------------------------------
// Kernel B (r8 form, UNSPLIT again — visibility round over): pipelined
// grid-stride attention, 5 tiles/block.  At pattern roofline (3.7 TB/s
// random 128B-line gathers; ILP- and occupancy-insensitive, r8/r9/r10).
// ---------------------------------------------------------------------------
__global__ __launch_bounds__(256) void attention_main(
    const unsigned char* __restrict__ P1,
    const unsigned char* __restrict__ M,
    const float* __restrict__ v_att,
    const int*   __restrict__ leaves, const int* __restrict__ anc,
    float*       __restrict__ out)
{
    const int t = threadIdx.x;
    const int wave = t >> 6, lane = t & 63;
    const int sub = lane >> 4, l16 = lane & 15;
    const int jj = l16 & 7;

    floatx2 vv[4];
    #pragma unroll
    for (int p = 0; p < 4; ++p)
        vv[p] = *(const floatx2*)(v_att + l16 * 8 + 2 * p);

    const int base = blockIdx.x;       // tiles: base + k*ATT_GRID

    auto idx_ptr = [&](int tile) -> const int* {
        const int n = tile * 16 + wave * 4 + sub;
        return (l16 & 8) ? (anc + n * 8 + jj) : (leaves + n * 8 + jj);
    };

    int    lf[2][NANC], an[2][NANC];
    uint2  R1[2][NANC], R2[2][NANC];
    short8 EM[NANC];
    int    raw[2];

    // ---- prologue: stage 0 fully issued, stage-1 index in flight ----
    raw[0] = __builtin_nontemporal_load(idx_ptr(base));
    #pragma unroll
    for (int a = 0; a < NANC; ++a) {
        lf[0][a] = __shfl(raw[0], (sub << 4) + a);
        an[0][a] = __shfl(raw[0], (sub << 4) + 8 + a);
    }
    #pragma unroll
    for (int a = 0; a < NANC; ++a)
        R1[0][a] = *(const uint2*)(P1 + (size_t)lf[0][a] * 128 + l16 * 8);
    #pragma unroll
    for (int a = 0; a < NANC; ++a)
        R2[0][a] = *(const uint2*)(M + (size_t)an[0][a] * 384 + l16 * 8);
    #pragma unroll
    for (int a = 0; a < NANC; ++a)
        EM[a] = *(const short8*)(M + (size_t)an[0][a] * 384 + 128 + l16 * 16);
    raw[1] = __builtin_nontemporal_load(idx_ptr(base + ATT_GRID));

    #pragma unroll
    for (int it = 0; it < ATT_TPB; ++it) {
        const int cur = it & 1, nx = cur ^ 1;
        const int tile = base + it * ATT_GRID;

        if (it + 1 < ATT_TPB) {
            #pragma unroll
            for (int a = 0; a < NANC; ++a) {
                lf[nx][a] = __shfl(raw[nx], (sub << 4) + a);
                an[nx][a] = __shfl(raw[nx], (sub << 4) + 8 + a);
            }
            #pragma unroll
            for (int a = 0; a < NANC; ++a)
                R1[nx][a] = *(const uint2*)(P1 + (size_t)lf[nx][a] * 128 + l16 * 8);
            #pragma unroll
            for (int a = 0; a < NANC; ++a)
                R2[nx][a] = *(const uint2*)(M + (size_t)an[nx][a] * 384 + l16 * 8);
        }
        if (it + 2 < ATT_TPB)
            raw[cur] = __builtin_nontemporal_load(idx_ptr(tile + 2 * ATT_GRID));

        const int n = tile * 16 + wave * 4 + sub;

        float q[NANC];
        #pragma unroll
        for (int a = 0; a < NANC; ++a) {
            const floatx2 z0 = fp8pair<false>(R1[cur][a].x) + fp8pair<false>(R2[cur][a].x);
            const floatx2 z1 = fp8pair<true >(R1[cur][a].x) + fp8pair<true >(R2[cur][a].x);
            const floatx2 z2 = fp8pair<false>(R1[cur][a].y) + fp8pair<false>(R2[cur][a].y);
            const floatx2 z3 = fp8pair<true >(R1[cur][a].y) + fp8pair<true >(R2[cur][a].y);
            floatx2 t0, t1, t2, t3;
            tanh2pk(z0, z1, t0, t1);
            tanh2pk(z2, z3, t2, t3);
            floatx2 qa = t0 * vv[0];
            qa = t1 * vv[1] + qa;
            qa = t2 * vv[2] + qa;
            qa = t3 * vv[3] + qa;
            q[a] = qa[0] + qa[1];
        }

        float r4[4];
        #pragma unroll
        for (int i = 0; i < 4; ++i) {
            const float keep = (l16 & 8) ? q[i + 4] : q[i];
            const float send = (l16 & 8) ? q[i]     : q[i + 4];
            r4[i] = keep + __shfl_xor(send, 8);
        }
        float s2[2];
        #pragma unroll
        for (int i = 0; i < 2; ++i) {
            const float keep = (l16 & 4) ? r4[i + 2] : r4[i];
            const float send = (l16 & 4) ? r4[i]     : r4[i + 2];
            s2[i] = keep + __shfl_xor(send, 4);
        }
        {
            const float keep = (l16 & 2) ? s2[1] : s2[0];
            const float send = (l16 & 2) ? s2[0] : s2[1];
            s2[0] = keep + __shfl_xor(send, 2);
        }
        float tq = s2[0] + __shfl_xor(s2[0], 1);   // lane holds q_total[A(l)]

        float m = tq;
        m = fmaxf(m, __shfl_xor(m, 8));
        m = fmaxf(m, __shfl_xor(m, 4));
        m = fmaxf(m, __shfl_xor(m, 2));
        const float e = __expf(tq - m);
        float s = e;
        s += __shfl_xor(s, 8); s += __shfl_xor(s, 4); s += __shfl_xor(s, 2);
        const float wl = e * __fdividef(1.0f, s);

        float wa[NANC];
        {
            const float p  = __shfl_xor(wl, 2);
            const float w0 = (l16 & 2) ? p  : wl;   // a-bit0 = 0
            const float w1 = (l16 & 2) ? wl : p;    // a-bit0 = 1
            const float p0 = __shfl_xor(w0, 4), p1 = __shfl_xor(w1, 4);
            const float v00 = (l16 & 4) ? p0 : w0, v01 = (l16 & 4) ? p1 : w1;
            const float v10 = (l16 & 4) ? w0 : p0, v11 = (l16 & 4) ? w1 : p1;
            float g;
            g = __shfl_xor(v00, 8); wa[0] = (l16 & 8) ? g : v00; wa[4] = (l16 & 8) ? v00 : g;
            g = __shfl_xor(v01, 8); wa[1] = (l16 & 8) ? g : v01; wa[5] = (l16 & 8) ? v01 : g;
            g = __shfl_xor(v10, 8); wa[2] = (l16 & 8) ? g : v10; wa[6] = (l16 & 8) ? v10 : g;
            g = __shfl_xor(v11, 8); wa[3] = (l16 & 8) ? g : v11; wa[7] = (l16 & 8) ? v11 : g;
        }

        floatx2 o[4] = {(floatx2)0.f, (floatx2)0.f, (floatx2)0.f, (floatx2)0.f};
        #pragma unroll
        for (int a = 0; a < NANC; ++a) {
            floatx2 wv; wv[0] = wa[a]; wv[1] = wa[a];
            #pragma unroll
            for (int p = 0; p < 4; ++p) {
                floatx2 ev;
                ev[0] = bf2f((ushort)EM[a][2 * p]);
                ev[1] = bf2f((ushort)EM[a][2 * p + 1]);
                o[p] = ev * wv + o[p];
            }
        }
        float4v o1, o2;
        o1[0] = o[0][0]; o1[1] = o[0][1]; o1[2] = o[1][0]; o1[3] = o[1][1];
        o2[0] = o[2][0]; o2[1] = o[2][1]; o2[2] = o[3][0]; o2[3] = o[3][1];
        __builtin_nontemporal_store(o1, (float4v*)(out + (size_t)n * 128 + l16 * 8));
        __builtin_nontemporal_store(o2, (float4v*)(out + (size_t)n * 128 + l16 * 8 + 4));

        if (it + 1 < ATT_TPB) {
            #pragma unroll
            for (int a = 0; a < NANC; ++a)
                EM[a] = *(const short8*)(M + (size_t)an[nx][a] * 384 + 128 + l16 * 16);
        }
    }
}

// ---------------------------------------------------------------------------
extern "C" void kernel_launch(void* const* d_in, const int* in_sizes, int n_in,
                              void* d_out, int out_size, void* d_ws, size_t ws_size,
                              hipStream_t stream) {
    const float* W_emb  = (const float*)d_in[0];
    const float* W_att  = (const float*)d_in[1];
    const float* b_att  = (const float*)d_in[2];
    const float* v_att  = (const float*)d_in[3];
    const int*   leaves = (const int*)d_in[4];
    const int*   anc    = (const int*)d_in[5];
    float*       out    = (float*)d_out;

    unsigned char* P1 = (unsigned char*)d_ws;            // 12.8 MB fp8
    unsigned char* M  = P1 + (size_t)VOCAB * 128;        // 38.4 MB merged
    ushort* WT = (ushort*)(M + (size_t)VOCAB * 384);     // 64 KB bf16

    transpose_watt<<<128, 256, 0, stream>>>(W_att, WT);
    precompute<<<PRE_GRID, 256, 0, stream>>>(W_emb, WT, b_att, P1, M);
    attention_main<<<ATT_GRID, 256, 0, stream>>>(P1, M, v_att,
                                                 leaves, anc, out);
}